// Round 1
// baseline (455.915 us; speedup 1.0000x reference)
//
#include <hip/hip_runtime.h>
#include <hip/hip_bf16.h>

// PoolAggregator: out[b,h] = mean_s relu( W @ features[idx[b,s]] + bias )
// B=10000, S=32, N=100000, D_IN=512, D_H=512.
// Strategy: gathered bf16 MFMA GEMM (M = B*S = 320000), fused bias+ReLU+mean epilogue.
// 128x128 tile (4 nodes x 32 neighbors), BK=64, 4 waves (2x2), 16x16x32 MFMA,
// XOR-swizzled LDS (T2), on-the-fly f32->bf16 conversion during staging.

#define S_NB 32
#define D_IN 512
#define D_H  512
#define BM   128
#define BN   128
#define BK   64

typedef __attribute__((ext_vector_type(8))) short  short8;   // 8 bf16 = 4 VGPR
typedef __attribute__((ext_vector_type(4))) float  f32x4;
typedef __attribute__((ext_vector_type(4))) unsigned short us4;

__device__ __forceinline__ unsigned short f2bf(float x) {
  // RNE float->bf16 (compiler may fuse pairs into v_cvt_pk_bf16_f32)
  union { float f; unsigned u; } v; v.f = x;
  unsigned r = v.u + 0x7FFFu + ((v.u >> 16) & 1u);
  return (unsigned short)(r >> 16);
}

// byte offset into a [128][64]-bf16 tile (row stride 128B) with st-style XOR swizzle
__device__ __forceinline__ int swz(int row, int cb) {
  return row * 128 + (cb ^ ((row & 7) << 4));
}

__global__ __launch_bounds__(256, 2)
void pool_aggr_gemm(const int* __restrict__ nidx_g,
                    const float* __restrict__ feat,
                    const float* __restrict__ Wm,
                    const float* __restrict__ bias,
                    float* __restrict__ out) {
  const int tid  = threadIdx.x;
  const int lane = tid & 63;
  const int wid  = tid >> 6;
  const int wr   = wid >> 1;             // wave row 0..1 (64 rows each)
  const int wc   = wid & 1;              // wave col 0..1 (64 cols each)
  const int n0   = blockIdx.x * BN;      // D_H tile base
  const int mb   = blockIdx.y;           // node group (4 nodes = 128 gathered rows)

  __shared__ __align__(16) unsigned short As[BM * BK];
  __shared__ __align__(16) unsigned short Bs[BM * BK];
  __shared__ int nid[BM];

  if (tid < BM) nid[tid] = nidx_g[mb * BM + tid];
  __syncthreads();

  // staging decomposition: 256 threads cover 128 rows x 64 cols (f32) per K-step
  // thread -> (row = p*16 + tid/16, float4 slot = tid%16), p = 0..7
  const int lr = tid >> 4;
  const int lc = tid & 15;

  const float* aptr[8];
  const float* wptr[8];
#pragma unroll
  for (int p = 0; p < 8; ++p) {
    int row = p * 16 + lr;
    aptr[p] = feat + (size_t)nid[row] * D_IN + lc * 4;
    wptr[p] = Wm + (size_t)(n0 + row) * D_IN + lc * 4;
  }

  f32x4 acc[4][4];
#pragma unroll
  for (int i = 0; i < 4; ++i)
#pragma unroll
    for (int j = 0; j < 4; ++j)
      acc[i][j] = (f32x4){0.f, 0.f, 0.f, 0.f};

  const int frow = lane & 15;        // fragment row/col within 16
  const int kcb  = (lane >> 4) * 16; // k-chunk byte offset (8 bf16 per lane)
  const int arow = wr * 64 + frow;
  const int brow = wc * 64 + frow;

  for (int k0 = 0; k0 < D_IN; k0 += BK) {
    __syncthreads();   // previous iteration's reads done before overwrite
#pragma unroll
    for (int p = 0; p < 8; ++p) {
      int row = p * 16 + lr;
      f32x4 av = *(const f32x4*)(aptr[p] + k0);
      f32x4 wv = *(const f32x4*)(wptr[p] + k0);
      us4 a4, w4;
      a4.x = f2bf(av.x); a4.y = f2bf(av.y); a4.z = f2bf(av.z); a4.w = f2bf(av.w);
      w4.x = f2bf(wv.x); w4.y = f2bf(wv.y); w4.z = f2bf(wv.z); w4.w = f2bf(wv.w);
      *(us4*)((char*)As + swz(row, lc * 8)) = a4;
      *(us4*)((char*)Bs + swz(row, lc * 8)) = w4;
    }
    __syncthreads();

#pragma unroll
    for (int kk = 0; kk < 2; ++kk) {
      short8 af[4], bfr[4];
#pragma unroll
      for (int mi = 0; mi < 4; ++mi)
        af[mi] = *(const short8*)((const char*)As + swz(arow + mi * 16, kk * 64 + kcb));
#pragma unroll
      for (int ni = 0; ni < 4; ++ni)
        bfr[ni] = *(const short8*)((const char*)Bs + swz(brow + ni * 16, kk * 64 + kcb));
#pragma unroll
      for (int mi = 0; mi < 4; ++mi)
#pragma unroll
        for (int ni = 0; ni < 4; ++ni)
          acc[mi][ni] = __builtin_amdgcn_mfma_f32_16x16x32_bf16(af[mi], bfr[ni], acc[mi][ni], 0, 0, 0);
    }
  }

  // Epilogue: C row (in wave tile) = mi*16 + (lane>>4)*4 + r ; col = ni*16 + (lane&15).
  // Each 32-row group (one graph node) = mi in {2*bl, 2*bl+1} x rq x r.
  const int rq = lane >> 4;
#pragma unroll
  for (int ni = 0; ni < 4; ++ni) {
    int col = n0 + wc * 64 + ni * 16 + frow;
    float bv = bias[col];
#pragma unroll
    for (int bl = 0; bl < 2; ++bl) {
      float s = 0.f;
#pragma unroll
      for (int m2 = 0; m2 < 2; ++m2) {
        int mi = bl * 2 + m2;
#pragma unroll
        for (int r = 0; r < 4; ++r)
          s += fmaxf(acc[mi][ni][r] + bv, 0.f);
      }
      s += __shfl_xor(s, 16);
      s += __shfl_xor(s, 32);
      if (rq == 0) {
        int bb = mb * 4 + wr * 2 + bl;   // global output node
        out[(size_t)bb * D_H + col] = s * (1.0f / (float)S_NB);
      }
    }
  }
}

extern "C" void kernel_launch(void* const* d_in, const int* in_sizes, int n_in,
                              void* d_out, int out_size, void* d_ws, size_t ws_size,
                              hipStream_t stream) {
  const int*   nidx = (const int*)d_in[0];    // [10000,32]
  const float* feat = (const float*)d_in[1];  // [100000,512]
  const float* Wm   = (const float*)d_in[2];  // [512,512]
  const float* bias = (const float*)d_in[3];  // [512]
  float* out = (float*)d_out;                 // [10000,512]

  dim3 grid(D_H / BN, 10000 / 4);   // (4, 2500); N-tile fastest for gather L2 reuse
  pool_aggr_gemm<<<grid, 256, 0, stream>>>(nidx, feat, Wm, bias, out);
}

// Round 2
// 431.740 us; speedup vs baseline: 1.0560x; 1.0560x over previous
//
#include <hip/hip_runtime.h>
#include <hip/hip_bf16.h>

// PoolAggregator: out[b,h] = mean_s relu( W @ features[idx[b,s]] + bias )
// B=10000, S=32, N=100000, D_IN=512, D_H=512.
//
// Key algebra: relu(W f + b) depends only on the node, not the sample.
// Phase 1: H[n,:] = relu(W @ features[n] + b) for ALL 100000 nodes -> bf16 in d_ws
//          (52.4 GFLOP instead of 167.8 for the sampled form).
// Phase 2: out[b,:] = mean_s H[idx[b,s],:]  (gather + mean, H is L3-resident).
// Fallback to the fused round-1 kernel if ws_size is too small.

#define S_NB 32
#define D_IN 512
#define D_H  512
#define BM   128
#define BN   128
#define BK   64
#define NNODE 100000
#define NBATCH 10000

typedef __attribute__((ext_vector_type(8))) short  short8;   // 8 bf16 = 4 VGPR
typedef __attribute__((ext_vector_type(4))) float  f32x4;
typedef __attribute__((ext_vector_type(4))) unsigned short us4;

__device__ __forceinline__ unsigned short f2bf(float x) {
  union { float f; unsigned u; } v; v.f = x;
  unsigned r = v.u + 0x7FFFu + ((v.u >> 16) & 1u);
  return (unsigned short)(r >> 16);
}

__device__ __forceinline__ float bf2f(unsigned short x) {
  union { unsigned u; float f; } v; v.u = ((unsigned)x) << 16;
  return v.f;
}

// byte offset into a [128][64]-bf16 tile (row stride 128B) with XOR swizzle (T2)
__device__ __forceinline__ int swz(int row, int cb) {
  return row * 128 + (cb ^ ((row & 7) << 4));
}

// ---------------- Phase 1: H = relu(feat @ W^T + b) -> bf16 ----------------
__global__ __launch_bounds__(256, 4)
void gemm_h(const float* __restrict__ feat,
            const float* __restrict__ Wm,
            const float* __restrict__ bias,
            unsigned short* __restrict__ Hb) {
  const int tid  = threadIdx.x;
  const int lane = tid & 63;
  const int wid  = tid >> 6;
  const int wr   = wid >> 1;
  const int wc   = wid & 1;
  const int n0   = blockIdx.x * BN;
  const int m0   = blockIdx.y * BM;

  __shared__ __align__(16) unsigned short As[BM * BK];
  __shared__ __align__(16) unsigned short Bs[BM * BK];

  const int lr = tid >> 4;
  const int lc = tid & 15;

  const float* aptr[8];
  const float* wptr[8];
#pragma unroll
  for (int p = 0; p < 8; ++p) {
    int row = p * 16 + lr;
    int gr  = m0 + row; if (gr > NNODE - 1) gr = NNODE - 1;   // clamp pad rows
    aptr[p] = feat + (size_t)gr * D_IN + lc * 4;
    wptr[p] = Wm + (size_t)(n0 + row) * D_IN + lc * 4;
  }

  f32x4 acc[4][4];
#pragma unroll
  for (int i = 0; i < 4; ++i)
#pragma unroll
    for (int j = 0; j < 4; ++j)
      acc[i][j] = (f32x4){0.f, 0.f, 0.f, 0.f};

  const int frow = lane & 15;
  const int kcb  = (lane >> 4) * 16;
  const int arow = wr * 64 + frow;
  const int brow = wc * 64 + frow;

  for (int k0 = 0; k0 < D_IN; k0 += BK) {
    __syncthreads();
#pragma unroll
    for (int p = 0; p < 8; ++p) {
      int row = p * 16 + lr;
      f32x4 av = *(const f32x4*)(aptr[p] + k0);
      f32x4 wv = *(const f32x4*)(wptr[p] + k0);
      us4 a4, w4;
      a4.x = f2bf(av.x); a4.y = f2bf(av.y); a4.z = f2bf(av.z); a4.w = f2bf(av.w);
      w4.x = f2bf(wv.x); w4.y = f2bf(wv.y); w4.z = f2bf(wv.z); w4.w = f2bf(wv.w);
      *(us4*)((char*)As + swz(row, lc * 8)) = a4;
      *(us4*)((char*)Bs + swz(row, lc * 8)) = w4;
    }
    __syncthreads();

#pragma unroll
    for (int kk = 0; kk < 2; ++kk) {
      short8 af[4], bfr[4];
#pragma unroll
      for (int mi = 0; mi < 4; ++mi)
        af[mi] = *(const short8*)((const char*)As + swz(arow + mi * 16, kk * 64 + kcb));
#pragma unroll
      for (int ni = 0; ni < 4; ++ni)
        bfr[ni] = *(const short8*)((const char*)Bs + swz(brow + ni * 16, kk * 64 + kcb));
#pragma unroll
      for (int mi = 0; mi < 4; ++mi)
#pragma unroll
        for (int ni = 0; ni < 4; ++ni)
          acc[mi][ni] = __builtin_amdgcn_mfma_f32_16x16x32_bf16(af[mi], bfr[ni], acc[mi][ni], 0, 0, 0);
    }
  }

  // Epilogue: C row = wr*64 + mi*16 + rq*4 + r ; col = n0 + wc*64 + ni*16 + frow.
  const int rq = lane >> 4;
#pragma unroll
  for (int ni = 0; ni < 4; ++ni) {
    int col = n0 + wc * 64 + ni * 16 + frow;
    float bv = bias[col];
#pragma unroll
    for (int mi = 0; mi < 4; ++mi) {
#pragma unroll
      for (int r = 0; r < 4; ++r) {
        int grow = m0 + wr * 64 + mi * 16 + rq * 4 + r;
        if (grow < NNODE)
          Hb[(size_t)grow * D_H + col] = f2bf(fmaxf(acc[mi][ni][r] + bv, 0.f));
      }
    }
  }
}

// ---------------- Phase 2: out[b,:] = mean_s H[idx[b,s],:] ----------------
__global__ __launch_bounds__(256, 8)
void pool_mean(const unsigned short* __restrict__ Hb,
               const int* __restrict__ nidx,
               float* __restrict__ out) {
  const int b   = blockIdx.x;
  const int tid = threadIdx.x;

  __shared__ int rows[S_NB];
  if (tid < S_NB) rows[tid] = nidx[b * S_NB + tid];
  __syncthreads();

  const int c2 = tid * 2;               // each thread owns 2 adjacent columns
  float s0 = 0.f, s1 = 0.f;
#pragma unroll
  for (int s = 0; s < S_NB; ++s) {
    unsigned v = *(const unsigned*)(Hb + (size_t)rows[s] * D_H + c2);
    s0 += bf2f((unsigned short)(v & 0xffffu));
    s1 += bf2f((unsigned short)(v >> 16));
  }
  float2 o; o.x = s0 * (1.0f / S_NB); o.y = s1 * (1.0f / S_NB);
  *(float2*)(out + (size_t)b * D_H + c2) = o;
}

// ---------------- Fallback: fused gathered GEMM (round-1 kernel) ----------------
__global__ __launch_bounds__(256, 4)
void pool_aggr_gemm(const int* __restrict__ nidx_g,
                    const float* __restrict__ feat,
                    const float* __restrict__ Wm,
                    const float* __restrict__ bias,
                    float* __restrict__ out) {
  const int tid  = threadIdx.x;
  const int lane = tid & 63;
  const int wid  = tid >> 6;
  const int wr   = wid >> 1;
  const int wc   = wid & 1;
  const int n0   = blockIdx.x * BN;
  const int mb   = blockIdx.y;

  __shared__ __align__(16) unsigned short As[BM * BK];
  __shared__ __align__(16) unsigned short Bs[BM * BK];
  __shared__ int nid[BM];

  if (tid < BM) nid[tid] = nidx_g[mb * BM + tid];
  __syncthreads();

  const int lr = tid >> 4;
  const int lc = tid & 15;

  const float* aptr[8];
  const float* wptr[8];
#pragma unroll
  for (int p = 0; p < 8; ++p) {
    int row = p * 16 + lr;
    aptr[p] = feat + (size_t)nid[row] * D_IN + lc * 4;
    wptr[p] = Wm + (size_t)(n0 + row) * D_IN + lc * 4;
  }

  f32x4 acc[4][4];
#pragma unroll
  for (int i = 0; i < 4; ++i)
#pragma unroll
    for (int j = 0; j < 4; ++j)
      acc[i][j] = (f32x4){0.f, 0.f, 0.f, 0.f};

  const int frow = lane & 15;
  const int kcb  = (lane >> 4) * 16;
  const int arow = wr * 64 + frow;
  const int brow = wc * 64 + frow;

  for (int k0 = 0; k0 < D_IN; k0 += BK) {
    __syncthreads();
#pragma unroll
    for (int p = 0; p < 8; ++p) {
      int row = p * 16 + lr;
      f32x4 av = *(const f32x4*)(aptr[p] + k0);
      f32x4 wv = *(const f32x4*)(wptr[p] + k0);
      us4 a4, w4;
      a4.x = f2bf(av.x); a4.y = f2bf(av.y); a4.z = f2bf(av.z); a4.w = f2bf(av.w);
      w4.x = f2bf(wv.x); w4.y = f2bf(wv.y); w4.z = f2bf(wv.z); w4.w = f2bf(wv.w);
      *(us4*)((char*)As + swz(row, lc * 8)) = a4;
      *(us4*)((char*)Bs + swz(row, lc * 8)) = w4;
    }
    __syncthreads();

#pragma unroll
    for (int kk = 0; kk < 2; ++kk) {
      short8 af[4], bfr[4];
#pragma unroll
      for (int mi = 0; mi < 4; ++mi)
        af[mi] = *(const short8*)((const char*)As + swz(arow + mi * 16, kk * 64 + kcb));
#pragma unroll
      for (int ni = 0; ni < 4; ++ni)
        bfr[ni] = *(const short8*)((const char*)Bs + swz(brow + ni * 16, kk * 64 + kcb));
#pragma unroll
      for (int mi = 0; mi < 4; ++mi)
#pragma unroll
        for (int ni = 0; ni < 4; ++ni)
          acc[mi][ni] = __builtin_amdgcn_mfma_f32_16x16x32_bf16(af[mi], bfr[ni], acc[mi][ni], 0, 0, 0);
    }
  }

  const int rq = lane >> 4;
#pragma unroll
  for (int ni = 0; ni < 4; ++ni) {
    int col = n0 + wc * 64 + ni * 16 + frow;
    float bv = bias[col];
#pragma unroll
    for (int bl = 0; bl < 2; ++bl) {
      float s = 0.f;
#pragma unroll
      for (int m2 = 0; m2 < 2; ++m2) {
        int mi = bl * 2 + m2;
#pragma unroll
        for (int r = 0; r < 4; ++r)
          s += fmaxf(acc[mi][ni][r] + bv, 0.f);
      }
      s += __shfl_xor(s, 16);
      s += __shfl_xor(s, 32);
      if (rq == 0) {
        int bb = mb * 4 + wr * 2 + bl;
        out[(size_t)bb * D_H + col] = s * (1.0f / (float)S_NB);
      }
    }
  }
}

extern "C" void kernel_launch(void* const* d_in, const int* in_sizes, int n_in,
                              void* d_out, int out_size, void* d_ws, size_t ws_size,
                              hipStream_t stream) {
  const int*   nidx = (const int*)d_in[0];    // [10000,32]
  const float* feat = (const float*)d_in[1];  // [100000,512]
  const float* Wm   = (const float*)d_in[2];  // [512,512]
  const float* bias = (const float*)d_in[3];  // [512]
  float* out = (float*)d_out;                 // [10000,512]

  const size_t h_bytes = (size_t)NNODE * D_H * sizeof(unsigned short);  // 102.4 MB

  if (ws_size >= h_bytes) {
    unsigned short* Hb = (unsigned short*)d_ws;
    dim3 g1(D_H / BN, (NNODE + BM - 1) / BM);   // (4, 782)
    gemm_h<<<g1, 256, 0, stream>>>(feat, Wm, bias, Hb);
    pool_mean<<<NBATCH, 256, 0, stream>>>(Hb, nidx, out);
  } else {
    dim3 grid(D_H / BN, NBATCH / 4);
    pool_aggr_gemm<<<grid, 256, 0, stream>>>(nidx, feat, Wm, bias, out);
  }
}